// Round 1
// 204.376 us; speedup vs baseline: 1.0056x; 1.0056x over previous
//
#include <hip/hip_runtime.h>

#define N_VERTS 53215
#define EXP_DIM 29
#define SHP_DIM 199
#define HEIGHT_F 450.0f
#define ASPECT_XY (224.0f / 450.0f)

// Full 64-lane wave sum on the VALU pipe via DPP row ops (gfx9-lineage CDNA):
//   row_shr:1,2,4,8  -> lane 15/31/47/63 hold their 16-lane row sums
//   row_bcast:15     -> lane 31 = sum(0..31), lane 63 = sum(32..63)
//   row_bcast:31     -> lane 63 = sum(0..63)
// old=0 + full row/bank masks + bound_ctrl makes OOB/masked lanes contribute
// 0, so no mask bookkeeping is needed. Replaces the ds_bpermute butterfly
// (DS pipe, 6-deep lgkmcnt-waited chain) with 6 dependent VALU adds.
#define DPP_ADD_STEP(s, ctrl)                                                  \
  s += __int_as_float(__builtin_amdgcn_update_dpp(                             \
      0, __float_as_int(s), (ctrl), 0xf, 0xf, true))

// Interleave six independent chains (2 vertices x 3 components) per step so
// DPP dependency latency is hidden by ILP.
#define WAVE_REDUCE_6(s0, s1, s2, s3, s4, s5, ctrl)                            \
  do {                                                                         \
    DPP_ADD_STEP(s0, ctrl); DPP_ADD_STEP(s1, ctrl); DPP_ADD_STEP(s2, ctrl);    \
    DPP_ADD_STEP(s3, ctrl); DPP_ADD_STEP(s4, ctrl); DPP_ADD_STEP(s5, ctrl);    \
  } while (0)

// Grid-stride, wave-per-2-vertices, no barriers, no LDS/DS ops at all.
// 36 coalesced 4B-lane loads issued back-to-back per iteration (2x the MLP of
// the previous version), then 30 FMAs, then a 6-step DPP tree reduce.
// __launch_bounds__(256,4): allow up to 128 VGPRs so the 36-deep load window
// isn't wait-serialized by a 64-VGPR cap (the old (256,8) bound forced <=64).
__global__ __launch_bounds__(256, 4) void pca_transform_kernel(
    const float* __restrict__ pose,       // 12
    const float* __restrict__ alpha_exp,  // 29
    const float* __restrict__ alpha_shp,  // 199
    const float* __restrict__ u_base,     // 3*N_VERTS
    const float* __restrict__ w_exp,      // 3*N_VERTS x 29
    const float* __restrict__ w_shp,      // 3*N_VERTS x 199
    float* __restrict__ out)              // N_VERTS x 3
{
    const int lane = threadIdx.x & 63;
    // Wave id is uniform across the wave; readfirstlane lets the compiler put
    // all per-group addressing in SGPRs (scalar base + lane*4 voffset) and
    // turn the u_base loads into s_loads.
    const int gwave =
        __builtin_amdgcn_readfirstlane((int)((blockIdx.x * blockDim.x + threadIdx.x) >> 6));
    const int nwaves = (int)((gridDim.x * blockDim.x) >> 6);

    // Pose is uniform + loop-invariant -> SGPRs.
    const float p0 = pose[0], p1 = pose[1], p2  = pose[2],  p3  = pose[3];
    const float p4 = pose[4], p5 = pose[5], p6  = pose[6],  p7  = pose[7];
    const float p8 = pose[8], p9 = pose[9], p10 = pose[10], p11 = pose[11];
    const float s  = p3 + p7 + p11;

    // Per-lane alpha slice is loop-invariant: hoist to registers.
    // 199 = 3*64 + 7 ; clamp tail address, zero the weight (no exec-mask br).
    const int  k3 = (lane < 7)  ? lane + 192 : 198;
    const int  ke = (lane < EXP_DIM) ? lane : (EXP_DIM - 1);
    const float a0 = alpha_shp[lane];
    const float a1 = alpha_shp[lane + 64];
    const float a2 = alpha_shp[lane + 128];
    const float a3 = (lane < 7) ? alpha_shp[k3] : 0.0f;
    const float ae = (lane < EXP_DIM) ? alpha_exp[ke] : 0.0f;

    const int ngroups = (N_VERTS + 1) >> 1;  // 26608, last group is a single
    for (int g = gwave; g < ngroups; g += nwaves) {
        const int v0 = g << 1;
        const int v1 = (v0 + 1 < N_VERTS) ? v0 + 1 : v0;  // tail: duplicate v0

        const float* __restrict__ A  = w_shp + (size_t)(3 * v0) * SHP_DIM;
        const float* __restrict__ B  = w_shp + (size_t)(3 * v1) * SHP_DIM;
        const float* __restrict__ EA = w_exp + (size_t)(3 * v0) * EXP_DIM;
        const float* __restrict__ EB = w_exp + (size_t)(3 * v1) * EXP_DIM;

        // ---- Issue all 36 loads back-to-back (max MLP), then compute. ----
        // Vertex 0: 3 rows of w_shp (coalesced lane-strided) + 3 rows of w_exp
        const float ax0 = A[lane],               ax1 = A[lane + 64];
        const float ax2 = A[lane + 128],         ax3 = A[k3];
        const float ay0 = A[SHP_DIM + lane],     ay1 = A[SHP_DIM + lane + 64];
        const float ay2 = A[SHP_DIM + lane + 128], ay3 = A[SHP_DIM + k3];
        const float az0 = A[2*SHP_DIM + lane],   az1 = A[2*SHP_DIM + lane + 64];
        const float az2 = A[2*SHP_DIM + lane + 128], az3 = A[2*SHP_DIM + k3];
        // Vertex 1
        const float bx0 = B[lane],               bx1 = B[lane + 64];
        const float bx2 = B[lane + 128],         bx3 = B[k3];
        const float by0 = B[SHP_DIM + lane],     by1 = B[SHP_DIM + lane + 64];
        const float by2 = B[SHP_DIM + lane + 128], by3 = B[SHP_DIM + k3];
        const float bz0 = B[2*SHP_DIM + lane],   bz1 = B[2*SHP_DIM + lane + 64];
        const float bz2 = B[2*SHP_DIM + lane + 128], bz3 = B[2*SHP_DIM + k3];
        // Exp rows (29 useful lanes, clamped+zero-weighted tail)
        const float aex = EA[ke], aey = EA[EXP_DIM + ke], aez = EA[2*EXP_DIM + ke];
        const float bex = EB[ke], bey = EB[EXP_DIM + ke], bez = EB[2*EXP_DIM + ke];
        // u_base: wave-uniform scalar loads, latency hidden under the FMAs.
        const float ux0 = u_base[3 * v0 + 0];
        const float uy0 = u_base[3 * v0 + 1];
        const float uz0 = u_base[3 * v0 + 2];
        const float ux1 = u_base[3 * v1 + 0];
        const float uy1 = u_base[3 * v1 + 1];
        const float uz1 = u_base[3 * v1 + 2];

        // Per-lane partial dot products (6 independent 5-FMA chains).
        float sx0 = ax0*a0 + ax1*a1 + ax2*a2 + ax3*a3 + aex*ae;
        float sy0 = ay0*a0 + ay1*a1 + ay2*a2 + ay3*a3 + aey*ae;
        float sz0 = az0*a0 + az1*a1 + az2*a2 + az3*a3 + aez*ae;
        float sx1 = bx0*a0 + bx1*a1 + bx2*a2 + bx3*a3 + bex*ae;
        float sy1 = by0*a0 + by1*a1 + by2*a2 + by3*a3 + bey*ae;
        float sz1 = bz0*a0 + bz1*a1 + bz2*a2 + bz3*a3 + bez*ae;

        // 6-step DPP tree reduce; totals land in lane 63.
        WAVE_REDUCE_6(sx0, sy0, sz0, sx1, sy1, sz1, 0x111);  // row_shr:1
        WAVE_REDUCE_6(sx0, sy0, sz0, sx1, sy1, sz1, 0x112);  // row_shr:2
        WAVE_REDUCE_6(sx0, sy0, sz0, sx1, sy1, sz1, 0x114);  // row_shr:4
        WAVE_REDUCE_6(sx0, sy0, sz0, sx1, sy1, sz1, 0x118);  // row_shr:8
        WAVE_REDUCE_6(sx0, sy0, sz0, sx1, sy1, sz1, 0x142);  // row_bcast:15
        WAVE_REDUCE_6(sx0, sy0, sz0, sx1, sy1, sz1, 0x143);  // row_bcast:31

        const float vx0 = sx0 + ux0, vy0 = sy0 + uy0, vz0 = sz0 + uz0;
        const float vx1 = sx1 + ux1, vy1 = sy1 + uy1, vz1 = sz1 + uz1;

        const float ox0 = ASPECT_XY * (s * (p0*vx0 + p1*vy0 + p2 *vz0) + p3);
        const float oy0 = ASPECT_XY * (HEIGHT_F - (s * (p4*vx0 + p5*vy0 + p6*vz0) + p7));
        const float oz0 = s * (p8*vx0 + p9*vy0 + p10*vz0);
        const float ox1 = ASPECT_XY * (s * (p0*vx1 + p1*vy1 + p2 *vz1) + p3);
        const float oy1 = ASPECT_XY * (HEIGHT_F - (s * (p4*vx1 + p5*vy1 + p6*vz1) + p7));
        const float oz1 = s * (p8*vx1 + p9*vy1 + p10*vz1);

        if (lane == 63) {
            float* o = out + (size_t)3 * v0;   // byte offset 24g -> 8B aligned
            if (v1 != v0) {
                *reinterpret_cast<float2*>(o)     = make_float2(ox0, oy0);
                *reinterpret_cast<float2*>(o + 2) = make_float2(oz0, ox1);
                *reinterpret_cast<float2*>(o + 4) = make_float2(oy1, oz1);
            } else {  // odd tail vertex
                o[0] = ox0; o[1] = oy0; o[2] = oz0;
            }
        }
    }
}

extern "C" void kernel_launch(void* const* d_in, const int* in_sizes, int n_in,
                              void* d_out, int out_size, void* d_ws, size_t ws_size,
                              hipStream_t stream) {
    const float* pose      = (const float*)d_in[0];
    const float* alpha_exp = (const float*)d_in[1];
    const float* alpha_shp = (const float*)d_in[2];
    const float* u_base    = (const float*)d_in[3];
    const float* w_exp     = (const float*)d_in[4];
    const float* w_shp     = (const float*)d_in[5];
    float* out = (float*)d_out;

    // 2048 blocks x 256 thr = 8192 waves; 2 vertices per wave-iteration,
    // ~3.25 groups per wave via grid-stride. 16 waves/CU at (256,4).
    pca_transform_kernel<<<2048, 256, 0, stream>>>(
        pose, alpha_exp, alpha_shp, u_base, w_exp, w_shp, out);
}